// Round 10
// baseline (141.556 us; speedup 1.0000x reference)
//
#include <hip/hip_runtime.h>
#include <hip/hip_fp16.h>

#define NSITES 262144

struct alignas(16) H8 { __half2 h[4]; };   // 8 fp16 values = 16 B
typedef __attribute__((ext_vector_type(2))) float floatx2;
typedef __attribute__((ext_vector_type(4))) unsigned int uintx4;

// ws layout:
//   G8 [NSITES][32] fp8 e4m3, site-major, 32 B/site   (8 MiB)   j = b*8+o
//   Sp [NSITES][32] fp16, site-major, 64 B/site       (16 MiB)

// One thread per (site, batch). Lane order b=t&3 -> stores are lane-consecutive.
__global__ __launch_bounds__(256) void prep_kernel(
    const float* __restrict__ In,       // [4][8][NSITES]
    const float* __restrict__ Weights,  // [8][8][16]
    const float* __restrict__ bias,     // [8][8]
    uint2* __restrict__ G8,             // [NSITES][4] quads of 8 fp8
    H8*    __restrict__ Sp)             // [NSITES][4]
{
    __shared__ float ws[8][8], wn[8][8], be[8];
    int t = threadIdx.x;
    if (t < 64) {
        int o = t >> 3, k = t & 7;
        float s0 = 0.f, s1 = 0.f;
        #pragma unroll
        for (int s = 0; s < 8; ++s) {
            s0 += Weights[s*128 + o*16 + k];
            s1 += Weights[s*128 + o*16 + 8 + k];
        }
        ws[o][k] = s0; wn[o][k] = s1;
    } else if (t < 72) {
        int o = t - 64;
        float s = 0.f;
        #pragma unroll
        for (int q = 0; q < 8; ++q) s += bias[q*8 + o];
        be[o] = s;
    }
    __syncthreads();

    int b    = t & 3;                    // batch (= quad index)
    int sl   = t >> 2;                   // 0..63
    int site = blockIdx.x * 64 + sl;

    float x[8];
    #pragma unroll
    for (int i = 0; i < 8; ++i)
        x[i] = In[(b*8 + i) * NSITES + site];   // 4×64B segments per wave-load

    float g[8], s[8];
    #pragma unroll
    for (int o = 0; o < 8; ++o) {
        float a0 = 0.f, a1 = be[o];
        #pragma unroll
        for (int i = 0; i < 8; ++i) {
            a0 = fmaf(wn[o][i], x[i], a0);
            a1 = fmaf(ws[o][i], x[i], a1);
        }
        g[o] = a0; s[o] = a1;
    }

    unsigned int w0 = 0, w1 = 0;
    w0 = __builtin_amdgcn_cvt_pk_fp8_f32(g[0], g[1], w0, false);
    w0 = __builtin_amdgcn_cvt_pk_fp8_f32(g[2], g[3], w0, true);
    w1 = __builtin_amdgcn_cvt_pk_fp8_f32(g[4], g[5], w1, false);
    w1 = __builtin_amdgcn_cvt_pk_fp8_f32(g[6], g[7], w1, true);
    G8[site*4 + b] = make_uint2(w0, w1);        // lane-consecutive 8B -> 512B/inst

    H8 sv;
    #pragma unroll
    for (int p = 0; p < 4; ++p) sv.h[p] = __floats2half2_rn(s[2*p], s[2*p+1]);
    Sp[site*4 + b] = sv;                        // lane-consecutive 16B -> 1KB/inst
}

// 4 lanes per site (as R8), but 2 independent sites per thread for MLP.
// All 24 NN indices prefetched; gathers issued in batches of 6 (3 z × 2 sites).
__global__ __launch_bounds__(256) void gather_kernel(
    const uintx4* __restrict__ Sp4,   // [NSITES][4] 16B fp16 quads
    const uint2*  __restrict__ G8,    // [NSITES][4] 8B fp8 quads
    const int*    __restrict__ NN,    // [13][NSITES], rows 1..12 used
    float*        __restrict__ out)   // [32][NSITES]
{
    __shared__ float lds[32][133];    // stride 133: conflict-free both phases
    int t    = threadIdx.x;           // 256
    int q    = t & 3;                 // comp quad (== batch b)
    int sl   = t >> 2;                // 0..63
    int base = blockIdx.x * 128;
    int n0   = base + sl;
    int n1   = base + 64 + sl;

    uintx4 sw0 = __builtin_nontemporal_load(Sp4 + n0*4 + q);
    uintx4 sw1 = __builtin_nontemporal_load(Sp4 + n1*4 + q);
    float sp0[8], sp1[8];
    #pragma unroll
    for (int p = 0; p < 4; ++p) {
        unsigned int wa = sw0[p], wb = sw1[p];
        __half2 ha, hb;
        __builtin_memcpy(&ha, &wa, 4);
        __builtin_memcpy(&hb, &wb, 4);
        float2 fa = __half22float2(ha), fb = __half22float2(hb);
        sp0[2*p] = fa.x; sp0[2*p+1] = fa.y;
        sp1[2*p] = fb.x; sp1[2*p+1] = fb.y;
    }

    int m0[12], m1[12];
    #pragma unroll
    for (int z = 0; z < 12; ++z) {
        m0[z] = __builtin_nontemporal_load(&NN[(z+1) * NSITES + n0]);
        m1[z] = __builtin_nontemporal_load(&NN[(z+1) * NSITES + n1]);
    }

    const float NLOG2E = -1.44269504f;
    float acc0[8], prod0[8], acc1[8], prod1[8];
    #pragma unroll
    for (int k = 0; k < 8; ++k) {
        acc0[k] = 0.f; prod0[k] = 1.f;
        acc1[k] = 0.f; prod1[k] = 1.f;
    }

    #pragma unroll
    for (int zz = 0; zz < 4; ++zz) {
        uint2 g0[3], g1[3];
        #pragma unroll
        for (int j = 0; j < 3; ++j) {
            g0[j] = G8[(size_t)m0[zz*3 + j] * 4 + q];   // 6 gathers in flight
            g1[j] = G8[(size_t)m1[zz*3 + j] * 4 + q];
        }
        #pragma unroll
        for (int j = 0; j < 3; ++j) {
            float ga[8], gb[8];
            floatx2 p;
            p = __builtin_amdgcn_cvt_pk_f32_fp8(g0[j].x, false); ga[0]=p[0]; ga[1]=p[1];
            p = __builtin_amdgcn_cvt_pk_f32_fp8(g0[j].x, true ); ga[2]=p[0]; ga[3]=p[1];
            p = __builtin_amdgcn_cvt_pk_f32_fp8(g0[j].y, false); ga[4]=p[0]; ga[5]=p[1];
            p = __builtin_amdgcn_cvt_pk_f32_fp8(g0[j].y, true ); ga[6]=p[0]; ga[7]=p[1];
            p = __builtin_amdgcn_cvt_pk_f32_fp8(g1[j].x, false); gb[0]=p[0]; gb[1]=p[1];
            p = __builtin_amdgcn_cvt_pk_f32_fp8(g1[j].x, true ); gb[2]=p[0]; gb[3]=p[1];
            p = __builtin_amdgcn_cvt_pk_f32_fp8(g1[j].y, false); gb[4]=p[0]; gb[5]=p[1];
            p = __builtin_amdgcn_cvt_pk_f32_fp8(g1[j].y, true ); gb[6]=p[0]; gb[7]=p[1];
            #pragma unroll
            for (int k = 0; k < 8; ++k) {
                float xa  = sp0[k] + ga[k];
                float axa = fabsf(xa);
                acc0[k] += fmaxf(xa, 0.f);
                prod0[k] = fmaf(prod0[k], __builtin_amdgcn_exp2f(axa * NLOG2E), prod0[k]);
                float xb  = sp1[k] + gb[k];
                float axb = fabsf(xb);
                acc1[k] += fmaxf(xb, 0.f);
                prod1[k] = fmaf(prod1[k], __builtin_amdgcn_exp2f(axb * NLOG2E), prod1[k]);
            }
        }
    }

    #pragma unroll
    for (int k = 0; k < 8; ++k) {
        lds[q*8 + k][sl]      = acc0[k] + 0.69314718f * __builtin_amdgcn_logf(prod0[k]);
        lds[q*8 + k][sl + 64] = acc1[k] + 0.69314718f * __builtin_amdgcn_logf(prod1[k]);
    }
    __syncthreads();

    int s  = t & 127;
    int j0 = t >> 7;                     // 0..1
    #pragma unroll
    for (int r = 0; r < 16; ++r) {
        int j = j0*16 + r;
        __builtin_nontemporal_store(lds[j][s], &out[j * NSITES + base + s]);
    }
}

extern "C" void kernel_launch(void* const* d_in, const int* in_sizes, int n_in,
                              void* d_out, int out_size, void* d_ws, size_t ws_size,
                              hipStream_t stream) {
    const float* In      = (const float*)d_in[0];
    const int*   NN      = (const int*)  d_in[1];
    const float* Weights = (const float*)d_in[2];
    const float* bias    = (const float*)d_in[3];
    float* out = (float*)d_out;

    uint2*  G8  = (uint2*)d_ws;                             // 8 MiB
    H8*     Sp  = (H8*)((char*)d_ws + (size_t)NSITES * 32); // 16 MiB
    uintx4* Sp4 = (uintx4*)Sp;

    prep_kernel<<<NSITES / 64, 256, 0, stream>>>(In, Weights, bias, G8, Sp);
    gather_kernel<<<NSITES / 128, 256, 0, stream>>>(Sp4, G8, NN, out);
}

// Round 11
// 140.558 us; speedup vs baseline: 1.0071x; 1.0071x over previous
//
#include <hip/hip_runtime.h>
#include <hip/hip_fp16.h>

#define NSITES 262144

struct alignas(16) H8 { __half2 h[4]; };   // 8 fp16 values = 16 B
typedef __attribute__((ext_vector_type(2))) float floatx2;
typedef __attribute__((ext_vector_type(4))) unsigned int uintx4;

// ws layout:
//   G8 [NSITES][32] fp8 e4m3, site-major, 32 B/site   (8 MiB)   j = b*8+o
//   Sp [NSITES][32] fp16, site-major, 64 B/site       (16 MiB)

// One thread per (site-pair, batch). Lane order b=t&3 -> stores lane-consecutive.
// 2 sites/thread: 16 independent In loads in flight (streaming ILP).
__global__ __launch_bounds__(256) void prep_kernel(
    const float* __restrict__ In,       // [4][8][NSITES]
    const float* __restrict__ Weights,  // [8][8][16]
    const float* __restrict__ bias,     // [8][8]
    uint2* __restrict__ G8,             // [NSITES][4] quads of 8 fp8
    H8*    __restrict__ Sp)             // [NSITES][4]
{
    __shared__ float ws[8][8], wn[8][8], be[8];
    int t = threadIdx.x;
    if (t < 64) {
        int o = t >> 3, k = t & 7;
        float s0 = 0.f, s1 = 0.f;
        #pragma unroll
        for (int s = 0; s < 8; ++s) {
            s0 += Weights[s*128 + o*16 + k];
            s1 += Weights[s*128 + o*16 + 8 + k];
        }
        ws[o][k] = s0; wn[o][k] = s1;
    } else if (t < 72) {
        int o = t - 64;
        float s = 0.f;
        #pragma unroll
        for (int q = 0; q < 8; ++q) s += bias[q*8 + o];
        be[o] = s;
    }
    __syncthreads();

    int b     = t & 3;                   // batch (= quad index)
    int sl    = t >> 2;                  // 0..63
    int site0 = blockIdx.x * 128 + sl;
    int site1 = site0 + 64;

    float x0[8], x1[8];
    #pragma unroll
    for (int i = 0; i < 8; ++i) {
        x0[i] = __builtin_nontemporal_load(&In[(b*8 + i) * NSITES + site0]);
        x1[i] = __builtin_nontemporal_load(&In[(b*8 + i) * NSITES + site1]);
    }

    #pragma unroll
    for (int v = 0; v < 2; ++v) {
        const float* x = v ? x1 : x0;
        int site = v ? site1 : site0;
        float g[8], s[8];
        #pragma unroll
        for (int o = 0; o < 8; ++o) {
            float a0 = 0.f, a1 = be[o];
            #pragma unroll
            for (int i = 0; i < 8; ++i) {
                a0 = fmaf(wn[o][i], x[i], a0);
                a1 = fmaf(ws[o][i], x[i], a1);
            }
            g[o] = a0; s[o] = a1;
        }

        unsigned int w0 = 0, w1 = 0;
        w0 = __builtin_amdgcn_cvt_pk_fp8_f32(g[0], g[1], w0, false);
        w0 = __builtin_amdgcn_cvt_pk_fp8_f32(g[2], g[3], w0, true);
        w1 = __builtin_amdgcn_cvt_pk_fp8_f32(g[4], g[5], w1, false);
        w1 = __builtin_amdgcn_cvt_pk_fp8_f32(g[6], g[7], w1, true);
        G8[site*4 + b] = make_uint2(w0, w1);    // lane-consecutive 8B -> 512B/inst

        unsigned int sw[4];
        #pragma unroll
        for (int p = 0; p < 4; ++p) {
            __half2 h = __floats2half2_rn(s[2*p], s[2*p+1]);
            __builtin_memcpy(&sw[p], &h, 4);
        }
        uintx4 svv = {sw[0], sw[1], sw[2], sw[3]};
        __builtin_nontemporal_store(svv, (uintx4*)Sp + site*4 + b);  // 1KB/inst
    }
}

// 4 lanes per site; lane owns 8 comps. G record = 32 B fp8, gather load = 8 B/lane.
// (exact R8 structure — measured at the ~3 TB/s random-HBM ceiling)
__global__ __launch_bounds__(256) void gather_kernel(
    const H8*    __restrict__ Sp,
    const uint2* __restrict__ G8,
    const int*   __restrict__ NN,    // [13][NSITES], rows 1..12 used
    float*       __restrict__ out)   // [32][NSITES]
{
    __shared__ float lds[32][65];
    int t    = threadIdx.x;        // 256
    int q    = t & 3;              // which 8-comp chunk
    int sl   = t >> 2;             // local site 0..63
    int base = blockIdx.x * 64;
    int n    = base + sl;

    // streaming (nt) load of Sp quad -> 8 floats
    uintx4 spw = __builtin_nontemporal_load((const uintx4*)Sp + (n*4 + q));
    float sp[8];
    #pragma unroll
    for (int p = 0; p < 4; ++p) {
        unsigned int w = spw[p];
        __half2 h; __builtin_memcpy(&h, &w, 4);
        float2 f = __half22float2(h);
        sp[2*p] = f.x; sp[2*p+1] = f.y;
    }

    const float NLOG2E = -1.44269504f;
    float acc[8], prod[8];
    #pragma unroll
    for (int k = 0; k < 8; ++k) { acc[k] = 0.f; prod[k] = 1.f; }

    #pragma unroll
    for (int z = 1; z < 13; ++z) {
        int m = __builtin_nontemporal_load(&NN[z * NSITES + n]);
        uint2 gw = G8[m*4 + q];
        float g[8];
        floatx2 p;
        p = __builtin_amdgcn_cvt_pk_f32_fp8(gw.x, false); g[0]=p[0]; g[1]=p[1];
        p = __builtin_amdgcn_cvt_pk_f32_fp8(gw.x, true ); g[2]=p[0]; g[3]=p[1];
        p = __builtin_amdgcn_cvt_pk_f32_fp8(gw.y, false); g[4]=p[0]; g[5]=p[1];
        p = __builtin_amdgcn_cvt_pk_f32_fp8(gw.y, true ); g[6]=p[0]; g[7]=p[1];
        #pragma unroll
        for (int k = 0; k < 8; ++k) {
            float x  = sp[k] + g[k];
            float ax = fabsf(x);
            acc[k] += fmaxf(x, 0.f);
            float e = __builtin_amdgcn_exp2f(ax * NLOG2E);  // e^-|x|
            prod[k] = fmaf(prod[k], e, prod[k]);            // Π (1+e^-|x|)  (≤ 2^12)
        }
    }

    #pragma unroll
    for (int k = 0; k < 8; ++k)
        lds[q*8 + k][sl] = acc[k] + 0.69314718f * __builtin_amdgcn_logf(prod[k]);
    __syncthreads();

    int s  = t & 63;
    int j0 = t >> 6;                     // 0..3
    #pragma unroll
    for (int r = 0; r < 8; ++r) {
        int j = j0*8 + r;
        __builtin_nontemporal_store(lds[j][s], &out[j * NSITES + base + s]);
    }
}

extern "C" void kernel_launch(void* const* d_in, const int* in_sizes, int n_in,
                              void* d_out, int out_size, void* d_ws, size_t ws_size,
                              hipStream_t stream) {
    const float* In      = (const float*)d_in[0];
    const int*   NN      = (const int*)  d_in[1];
    const float* Weights = (const float*)d_in[2];
    const float* bias    = (const float*)d_in[3];
    float* out = (float*)d_out;

    uint2* G8 = (uint2*)d_ws;                             // 8 MiB
    H8*    Sp = (H8*)((char*)d_ws + (size_t)NSITES * 32); // 16 MiB

    prep_kernel<<<NSITES / 128, 256, 0, stream>>>(In, Weights, bias, G8, Sp);
    gather_kernel<<<NSITES / 64, 256, 0, stream>>>(Sp, G8, NN, out);
}

// Round 12
// 136.418 us; speedup vs baseline: 1.0377x; 1.0303x over previous
//
#include <hip/hip_runtime.h>
#include <hip/hip_fp16.h>

#define NSITES 262144

struct alignas(16) H8 { __half2 h[4]; };   // 8 fp16 values = 16 B
typedef __attribute__((ext_vector_type(2))) float floatx2;
typedef __attribute__((ext_vector_type(4))) unsigned int uintx4;

// ws layout:
//   G8 [NSITES][32] fp8 e4m3, site-major, 32 B/site   (8 MiB)   j = b*8+o
//   Sp [NSITES][32] fp16, site-major, 64 B/site       (16 MiB)

// One thread per (site, batch). Lane order b=t&3 -> stores are lane-consecutive.
// (R8-exact prep: best measured)
__global__ __launch_bounds__(256) void prep_kernel(
    const float* __restrict__ In,       // [4][8][NSITES]
    const float* __restrict__ Weights,  // [8][8][16]
    const float* __restrict__ bias,     // [8][8]
    uint2* __restrict__ G8,             // [NSITES][4] quads of 8 fp8
    H8*    __restrict__ Sp)             // [NSITES][4]
{
    __shared__ float ws[8][8], wn[8][8], be[8];
    int t = threadIdx.x;
    if (t < 64) {
        int o = t >> 3, k = t & 7;
        float s0 = 0.f, s1 = 0.f;
        #pragma unroll
        for (int s = 0; s < 8; ++s) {
            s0 += Weights[s*128 + o*16 + k];
            s1 += Weights[s*128 + o*16 + 8 + k];
        }
        ws[o][k] = s0; wn[o][k] = s1;
    } else if (t < 72) {
        int o = t - 64;
        float s = 0.f;
        #pragma unroll
        for (int q = 0; q < 8; ++q) s += bias[q*8 + o];
        be[o] = s;
    }
    __syncthreads();

    int b    = t & 3;                    // batch (= quad index)
    int sl   = t >> 2;                   // 0..63
    int site = blockIdx.x * 64 + sl;

    float x[8];
    #pragma unroll
    for (int i = 0; i < 8; ++i)
        x[i] = In[(b*8 + i) * NSITES + site];   // 4×64B segments per wave-load

    float g[8], s[8];
    #pragma unroll
    for (int o = 0; o < 8; ++o) {
        float a0 = 0.f, a1 = be[o];
        #pragma unroll
        for (int i = 0; i < 8; ++i) {
            a0 = fmaf(wn[o][i], x[i], a0);
            a1 = fmaf(ws[o][i], x[i], a1);
        }
        g[o] = a0; s[o] = a1;
    }

    unsigned int w0 = 0, w1 = 0;
    w0 = __builtin_amdgcn_cvt_pk_fp8_f32(g[0], g[1], w0, false);
    w0 = __builtin_amdgcn_cvt_pk_fp8_f32(g[2], g[3], w0, true);
    w1 = __builtin_amdgcn_cvt_pk_fp8_f32(g[4], g[5], w1, false);
    w1 = __builtin_amdgcn_cvt_pk_fp8_f32(g[6], g[7], w1, true);
    G8[site*4 + b] = make_uint2(w0, w1);        // lane-consecutive 8B -> 512B/inst

    H8 sv;
    #pragma unroll
    for (int p = 0; p < 4; ++p) sv.h[p] = __floats2half2_rn(s[2*p], s[2*p+1]);
    Sp[site*4 + b] = sv;                        // lane-consecutive 16B -> 1KB/inst
}

// R8 geometry (4 lanes/site, 64-site tile, 8B gathers) + ONLY change:
// all 12 G loads issued before any math (explicit arrays + sched_barrier).
__global__ __launch_bounds__(256) void gather_kernel(
    const H8*    __restrict__ Sp,
    const uint2* __restrict__ G8,
    const int*   __restrict__ NN,    // [13][NSITES], rows 1..12 used
    float*       __restrict__ out)   // [32][NSITES]
{
    __shared__ float lds[32][65];
    int t    = threadIdx.x;        // 256
    int q    = t & 3;              // which 8-comp chunk
    int sl   = t >> 2;             // local site 0..63
    int base = blockIdx.x * 64;
    int n    = base + sl;

    // streaming (nt) load of Sp quad -> 8 floats
    uintx4 spw = __builtin_nontemporal_load((const uintx4*)Sp + (n*4 + q));
    float sp[8];
    #pragma unroll
    for (int p = 0; p < 4; ++p) {
        unsigned int w = spw[p];
        __half2 h; __builtin_memcpy(&h, &w, 4);
        float2 f = __half22float2(h);
        sp[2*p] = f.x; sp[2*p+1] = f.y;
    }

    int m[12];
    #pragma unroll
    for (int z = 0; z < 12; ++z)
        m[z] = __builtin_nontemporal_load(&NN[(z+1) * NSITES + n]);

    uint2 gw[12];
    #pragma unroll
    for (int z = 0; z < 12; ++z)
        gw[z] = G8[(size_t)m[z]*4 + q];          // 12 gathers in flight
    __builtin_amdgcn_sched_barrier(0);           // don't sink loads into math

    const float NLOG2E = -1.44269504f;
    float acc[8], prod[8];
    #pragma unroll
    for (int k = 0; k < 8; ++k) { acc[k] = 0.f; prod[k] = 1.f; }

    #pragma unroll
    for (int z = 0; z < 12; ++z) {
        float g[8];
        floatx2 p;
        p = __builtin_amdgcn_cvt_pk_f32_fp8(gw[z].x, false); g[0]=p[0]; g[1]=p[1];
        p = __builtin_amdgcn_cvt_pk_f32_fp8(gw[z].x, true ); g[2]=p[0]; g[3]=p[1];
        p = __builtin_amdgcn_cvt_pk_f32_fp8(gw[z].y, false); g[4]=p[0]; g[5]=p[1];
        p = __builtin_amdgcn_cvt_pk_f32_fp8(gw[z].y, true ); g[6]=p[0]; g[7]=p[1];
        #pragma unroll
        for (int k = 0; k < 8; ++k) {
            float x  = sp[k] + g[k];
            float ax = fabsf(x);
            acc[k] += fmaxf(x, 0.f);
            float e = __builtin_amdgcn_exp2f(ax * NLOG2E);  // e^-|x|
            prod[k] = fmaf(prod[k], e, prod[k]);            // Π (1+e^-|x|)  (≤ 2^12)
        }
    }

    #pragma unroll
    for (int k = 0; k < 8; ++k)
        lds[q*8 + k][sl] = acc[k] + 0.69314718f * __builtin_amdgcn_logf(prod[k]);
    __syncthreads();

    int s  = t & 63;
    int j0 = t >> 6;                     // 0..3
    #pragma unroll
    for (int r = 0; r < 8; ++r) {
        int j = j0*8 + r;
        __builtin_nontemporal_store(lds[j][s], &out[j * NSITES + base + s]);
    }
}

extern "C" void kernel_launch(void* const* d_in, const int* in_sizes, int n_in,
                              void* d_out, int out_size, void* d_ws, size_t ws_size,
                              hipStream_t stream) {
    const float* In      = (const float*)d_in[0];
    const int*   NN      = (const int*)  d_in[1];
    const float* Weights = (const float*)d_in[2];
    const float* bias    = (const float*)d_in[3];
    float* out = (float*)d_out;

    uint2* G8 = (uint2*)d_ws;                             // 8 MiB
    H8*    Sp = (H8*)((char*)d_ws + (size_t)NSITES * 32); // 16 MiB

    prep_kernel<<<NSITES / 64, 256, 0, stream>>>(In, Weights, bias, G8, Sp);
    gather_kernel<<<NSITES / 64, 256, 0, stream>>>(Sp, G8, NN, out);
}